// Round 4
// baseline (204.451 us; speedup 1.0000x reference)
//
#include <hip/hip_runtime.h>
#include <hip/hip_fp16.h>

typedef _Float16 half8 __attribute__((ext_vector_type(8)));
typedef float f32x4 __attribute__((ext_vector_type(4)));

#define BHSZ 16777216  // 65536 * 256

#define WAITL()  asm volatile("s_waitcnt lgkmcnt(0)" ::: "memory")
#define SBAR()   __builtin_amdgcn_s_barrier()
#define SCHEDB() __builtin_amdgcn_sched_barrier(0)

__device__ __forceinline__ float fast_sigmoid(float z) {
  float e = __builtin_amdgcn_exp2f(-z * 1.4426950408889634f);
  return __builtin_amdgcn_rcpf(1.0f + e);
}

__device__ __forceinline__ float fast_tanh(float z) {
  float a = __builtin_fabsf(z);
  float e = __builtin_amdgcn_exp2f(a * 2.8853900817779268f);
  float t = 1.0f - 2.0f * __builtin_amdgcn_rcpf(1.0f + e);
  return z < 0.0f ? -t : t;
}

// ---------------------------------------------------------------------------
// pack_b: Bp[N'][k] fp16 (B^T, N'-major), gate-interleaved columns:
//   N' = t*64 + g*16 + j -> logical col cl = t*16 + j, gate g (0=f,1=i,2=o,3=c)
// ---------------------------------------------------------------------------
__global__ __launch_bounds__(256) void pack_b(
    const float* __restrict__ Wf, const float* __restrict__ Uf,
    const float* __restrict__ Wi, const float* __restrict__ Ui,
    const float* __restrict__ Wo, const float* __restrict__ Uo,
    const float* __restrict__ Wc, const float* __restrict__ Uc,
    _Float16* __restrict__ Bp) {
  int idx = blockIdx.x * 256 + threadIdx.x;  // [0, 524288)
  int k = idx & 511;
  int Np = idx >> 9;
  int g = (Np >> 4) & 3;
  int cl = ((Np >> 6) << 4) | (Np & 15);
  const float* W;
  const float* U;
  switch (g) {
    case 0: W = Wf; U = Uf; break;
    case 1: W = Wi; U = Ui; break;
    case 2: W = Wo; U = Uo; break;
    default: W = Wc; U = Uc; break;
  }
  float v = (k < 256) ? W[k * 256 + cl] : U[(k - 256) * 256 + cl];
  Bp[idx] = (_Float16)v;
}

// ---------------------------------------------------------------------------
// lstm_fused: BM=64, BN'=256, 4 waves of 64x64 (acc 4x4 frags = 64 regs).
// A: fp32 global -> reg cvt -> ring-2 LDS (8 KB total), shared by all waves.
// B: MFMA fragments loaded DIRECT from global (Bp is 1 MB, L2-resident).
// 1 raw s_barrier per K-step, lgkmcnt-only waits; global loads stay in
// flight across barriers (1-step reg lookahead, compiler-counted vmcnt).
// Low regs (~140 unified) -> 3 waves/SIMD -> 3 independent blocks/CU.
// grid = 4096; XCD-grouped, bn-fastest (4 bn of one bm co-resident per XCD).
// ---------------------------------------------------------------------------
__global__ __launch_bounds__(256) void lstm_fused(
    const float* __restrict__ x, const float* __restrict__ h,
    const _Float16* __restrict__ Bp, const float* __restrict__ cin,
    const float* __restrict__ bf_, const float* __restrict__ bi_,
    const float* __restrict__ bo_, const float* __restrict__ bc_,
    float* __restrict__ out) {
  __shared__ _Float16 As[2][64 * 32];  // 4 KB per buffer

  int tid = threadIdx.x;
  int w = tid >> 6, l = tid & 63;
  int l15 = l & 15, lg = l >> 4;

  // XCD grouping: chunk = bid&7 (XCD), 512 wgs each; bn fastest within chunk.
  int bid = blockIdx.x;
  int wg = (bid & 7) * 512 + (bid >> 3);
  int bm = wg >> 2, bn = wg & 3;

  // --- A staging: thread -> row tid>>2 (16 rows/wave), 32B chunk aq = tid&3.
  int arow = tid >> 2, aq = tid & 3;
  const float* aSrcX = x + (long)(bm * 64 + arow) * 256 + aq * 8;
  const float* aSrcH = h + (long)(bm * 64 + arow) * 256 + aq * 8;
  // LDS row = 32 halves = 4 slots of 8; slot swizzle ^((row>>1)&3) -> 2-way max
  int aW = arow * 32 + ((aq ^ ((arow >> 1) & 3)) << 3);

  // --- A fragment read offsets (all 4 waves read the same 64-row tile)
  int offA[4];
#pragma unroll
  for (int mf = 0; mf < 4; ++mf) {
    int row = mf * 16 + l15;
    offA[mf] = row * 32 + ((lg ^ ((row >> 1) & 3)) << 3);
  }

  // --- B fragment bases (direct global): n-row = bn*256 + w*64 + nf*16 + l15
  const _Float16* bBase[4];
#pragma unroll
  for (int nf = 0; nf < 4; ++nf) {
    int nrow = bn * 256 + w * 64 + nf * 16 + l15;
    bBase[nf] = Bp + (long)nrow * 512 + lg * 8;
  }

  f32x4 acc[4][4];
#pragma unroll
  for (int a2 = 0; a2 < 4; ++a2)
#pragma unroll
    for (int b2 = 0; b2 < 4; ++b2)
      acc[a2][b2] = (f32x4){0.f, 0.f, 0.f, 0.f};

  float4 rpA[2][2];  // A fp32 lookahead (static-indexed under full unroll)
  half8 rpB[2][4];   // B fragment lookahead

  auto issueA = [&](int t, int s) {
    const float* p = ((t < 8) ? aSrcX : aSrcH) + (t & 7) * 32;
    rpA[s][0] = *reinterpret_cast<const float4*>(p);
    rpA[s][1] = *reinterpret_cast<const float4*>(p + 4);
  };
  auto issueB = [&](int t, int s) {
#pragma unroll
    for (int nf = 0; nf < 4; ++nf)
      rpB[s][nf] = *reinterpret_cast<const half8*>(bBase[nf] + t * 32);
  };
  auto cvtWrite = [&](int s, int slot) {
    half8 o;
    o[0] = (_Float16)rpA[s][0].x; o[1] = (_Float16)rpA[s][0].y;
    o[2] = (_Float16)rpA[s][0].z; o[3] = (_Float16)rpA[s][0].w;
    o[4] = (_Float16)rpA[s][1].x; o[5] = (_Float16)rpA[s][1].y;
    o[6] = (_Float16)rpA[s][1].z; o[7] = (_Float16)rpA[s][1].w;
    *reinterpret_cast<half8*>(&As[slot][aW]) = o;
  };

  // Prologue: A(0) -> LDS slot 0; B(0) stays in flight across the barrier.
  issueA(0, 0);
  issueB(0, 0);
  cvtWrite(0, 0);  // auto-waits A(0) only (B(0) newer, stays in flight)
  WAITL();
  SBAR();

#pragma unroll
  for (int t = 0; t < 16; ++t) {
    if (t < 15) {
      issueA(t + 1, (t + 1) & 1);  // A first: cvt-wait keeps B(t+1) in flight
      issueB(t + 1, (t + 1) & 1);
    }
    half8 av[4];
#pragma unroll
    for (int mf = 0; mf < 4; ++mf)
      av[mf] = *reinterpret_cast<const half8*>(&As[t & 1][offA[mf]]);
    __builtin_amdgcn_s_setprio(1);
#pragma unroll
    for (int mf = 0; mf < 4; ++mf)
#pragma unroll
      for (int nf = 0; nf < 4; ++nf)
        acc[mf][nf] = __builtin_amdgcn_mfma_f32_16x16x32_f16(
            av[mf], rpB[t & 1][nf], acc[mf][nf], 0, 0, 0);
    __builtin_amdgcn_s_setprio(0);
    SCHEDB();  // keep the A(t+1) vmcnt-wait (in cvtWrite) after the MFMAs
    if (t < 15) {
      // Writes slot (t+1)&1: its last readers finished at step t-1, ordered
      // by the barrier we already passed. LDS visibility needs lgkm only --
      // global loads target registers, so NO vmcnt wait at the barrier.
      cvtWrite((t + 1) & 1, (t + 1) & 1);
      WAITL();
      SBAR();
    }
  }

  // --- Epilogue: n-frag == gate (0=f,1=i,2=o,3=c); C/D: col=lane&15,
  // row=(lane>>4)*4+reg.
  int col = (bn * 4 + w) * 16 + l15;  // logical column in [0,256)
  float vbf = bf_[col], vbi = bi_[col], vbo = bo_[col], vbc = bc_[col];
#pragma unroll
  for (int mf = 0; mf < 4; ++mf) {
#pragma unroll
    for (int r = 0; r < 4; ++r) {
      long row = (long)(bm * 64 + mf * 16 + lg * 4 + r);
      float zf = acc[mf][0][r] + vbf;
      float zi = acc[mf][1][r] + vbi;
      float zo = acc[mf][2][r] + vbo;
      float zg = acc[mf][3][r] + vbc;
      float fg = fast_sigmoid(zf);
      float ig = fast_sigmoid(zi);
      float og = fast_sigmoid(zo);
      float gg = fast_tanh(zg);
      float cv = cin[row * 256 + col];
      float cn = cv * fg + gg * ig;
      float hn = og * fast_tanh(cn);
      out[row * 256 + col] = cn;
      out[BHSZ + row * 256 + col] = hn;
    }
  }
}

// ---------------------------------------------------------------------------
extern "C" void kernel_launch(void* const* d_in, const int* in_sizes, int n_in,
                              void* d_out, int out_size, void* d_ws, size_t ws_size,
                              hipStream_t stream) {
  const float* x  = (const float*)d_in[0];
  const float* c  = (const float*)d_in[1];
  const float* h  = (const float*)d_in[2];
  const float* Wi = (const float*)d_in[3];
  const float* Ui = (const float*)d_in[4];
  const float* bi = (const float*)d_in[5];
  const float* Wf = (const float*)d_in[6];
  const float* Uf = (const float*)d_in[7];
  const float* bf = (const float*)d_in[8];
  const float* Wc = (const float*)d_in[9];
  const float* Uc = (const float*)d_in[10];
  const float* bc = (const float*)d_in[11];
  const float* Wo = (const float*)d_in[12];
  const float* Uo = (const float*)d_in[13];
  const float* bo = (const float*)d_in[14];

  _Float16* Bp = (_Float16*)d_ws;  // 1 MB packed weights

  pack_b<<<2048, 256, 0, stream>>>(Wf, Uf, Wi, Ui, Wo, Uo, Wc, Uc, Bp);
  lstm_fused<<<4096, 256, 0, stream>>>(x, h, Bp, c, bf, bi, bo, bc,
                                       (float*)d_out);
}

// Round 5
// 139.283 us; speedup vs baseline: 1.4679x; 1.4679x over previous
//
#include <hip/hip_runtime.h>
#include <hip/hip_fp16.h>

typedef _Float16 half8 __attribute__((ext_vector_type(8)));
typedef float f32x4 __attribute__((ext_vector_type(4)));

#define BHSZ 16777216  // 65536 * 256
#define SLOT_BYTES 49152
#define B_OFF 32768

#define SBAR() __builtin_amdgcn_s_barrier()

__device__ __forceinline__ void gload16(const void* g, const void* lds) {
  __builtin_amdgcn_global_load_lds((const __attribute__((address_space(1))) void*)g,
                                   (__attribute__((address_space(3))) void*)lds,
                                   16, 0, 0);
}

__device__ __forceinline__ float fast_sigmoid(float z) {
  float e = __builtin_amdgcn_exp2f(-z * 1.4426950408889634f);
  return __builtin_amdgcn_rcpf(1.0f + e);
}

__device__ __forceinline__ float fast_tanh(float z) {
  float a = __builtin_fabsf(z);
  float e = __builtin_amdgcn_exp2f(a * 2.8853900817779268f);
  float t = 1.0f - 2.0f * __builtin_amdgcn_rcpf(1.0f + e);
  return z < 0.0f ? -t : t;
}

// ---------------------------------------------------------------------------
// pack_b: Bp[N'][k] fp16 (B^T, N'-major), gate-interleaved columns:
//   N' = t*64 + g*16 + j -> logical col cl = t*16 + j, gate g (0=f,1=i,2=o,3=c)
// ---------------------------------------------------------------------------
__global__ __launch_bounds__(256) void pack_b(
    const float* __restrict__ Wf, const float* __restrict__ Uf,
    const float* __restrict__ Wi, const float* __restrict__ Ui,
    const float* __restrict__ Wo, const float* __restrict__ Uo,
    const float* __restrict__ Wc, const float* __restrict__ Uc,
    _Float16* __restrict__ Bp) {
  int idx = blockIdx.x * 256 + threadIdx.x;  // [0, 524288)
  int k = idx & 511;
  int Np = idx >> 9;
  int g = (Np >> 4) & 3;
  int cl = ((Np >> 6) << 4) | (Np & 15);
  const float* W;
  const float* U;
  switch (g) {
    case 0: W = Wf; U = Uf; break;
    case 1: W = Wi; U = Ui; break;
    case 2: W = Wo; U = Uo; break;
    default: W = Wc; U = Uc; break;
  }
  float v = (k < 256) ? W[k * 256 + cl] : U[(k - 256) * 256 + cl];
  Bp[idx] = (_Float16)v;
}

// ---------------------------------------------------------------------------
// lstm_fused: BM=256, BN'=256, BK=64, 512 threads (8 waves, 2M x 4N,
// wave tile 128x64, acc 8x4 f32x4 = 128 regs). m201-style counted-vmcnt
// schedule over a 3-slot k-half ring:
//   slot = {A: 256x32 fp32 (32KB), B: 256x32 fp16 (16KB)} staged entirely by
//   global_load_lds (6 per thread per half); A converted fp32->fp16 at
//   fragment read time. 16 phases; phase j: vmcnt(6) [only half j+1 in
//   flight], s_barrier, stage half j+2, ds_read + cvt + 32 MFMA.
//   vmcnt never drains to 0 until the final phase.
// grid = 1024; XCD-grouped, bn-fastest.
// ---------------------------------------------------------------------------
__global__ __launch_bounds__(512, 2) void lstm_fused(
    const float* __restrict__ x, const float* __restrict__ h,
    const _Float16* __restrict__ Bp, const float* __restrict__ cin,
    const float* __restrict__ bf_, const float* __restrict__ bi_,
    const float* __restrict__ bo_, const float* __restrict__ bc_,
    float* __restrict__ out) {
  extern __shared__ __align__(16) char smem[];  // 3 * 49152 = 147456 B

  int tid = threadIdx.x;
  int w = tid >> 6, l = tid & 63;
  int l15 = l & 15, lg = l >> 4;
  int wr = w >> 2, wcn = w & 3;

  // XCD grouping: 1024 wgs, 128 per XCD; bn fastest (4 bn of one bm adjacent).
  int bid = blockIdx.x;
  int wg = (bid & 7) * 128 + (bid >> 3);
  int bm = wg >> 2, bn = wg & 3;

  // --- staging source offsets (per-lane, k-base added per phase) ---
  // A: 4 chunks; idx = p*512+tid; LDS row r = idx>>3, 16B slot s = idx&7.
  // content: A_lds[r][s] = src[bm*256+r][ kb + (s^(r&7))*4 .. +4 ]
  int fA[4];
#pragma unroll
  for (int p = 0; p < 4; ++p) {
    int idx = p * 512 + tid;
    int r = idx >> 3, s = idx & 7;
    fA[p] = (bm * 256 + r) * 256 + ((s ^ (r & 7)) << 2);
  }
  // B: 2 chunks; idx = p*512+tid; row r = idx>>2, slot s = idx&3 (16B = 8 h)
  int fB[2];
#pragma unroll
  for (int p = 0; p < 2; ++p) {
    int idx = p * 512 + tid;
    int r = idx >> 2, s = idx & 3;
    fB[p] = (bn * 256 + r) * 512 + ((s ^ (r & 3)) << 3);
  }
  // wave-uniform LDS dest bases (HW adds lane*16)
  int ldsA[4], ldsB[2];
#pragma unroll
  for (int p = 0; p < 4; ++p) ldsA[p] = (p * 512 + w * 64) * 16;
#pragma unroll
  for (int p = 0; p < 2; ++p) ldsB[p] = B_OFF + (p * 512 + w * 64) * 16;

  // --- fragment read byte-offsets within a slot ---
  int offA[8][2], offB[4];
#pragma unroll
  for (int mf = 0; mf < 8; ++mf) {
    int r = wr * 128 + mf * 16 + l15;
#pragma unroll
    for (int b = 0; b < 2; ++b)
      offA[mf][b] = r * 128 + (((lg * 2 + b) ^ (r & 7)) << 4);
  }
#pragma unroll
  for (int nf = 0; nf < 4; ++nf) {
    int r = wcn * 64 + nf * 16 + l15;
    offB[nf] = B_OFF + r * 64 + ((lg ^ (r & 3)) << 4);
  }

  f32x4 acc[8][4];
#pragma unroll
  for (int a2 = 0; a2 < 8; ++a2)
#pragma unroll
    for (int b2 = 0; b2 < 4; ++b2)
      acc[a2][b2] = (f32x4){0.f, 0.f, 0.f, 0.f};

  auto stage = [&](int j2) {  // j2 = k-half index 0..15, slot j2%3
    char* db = smem + (j2 % 3) * SLOT_BYTES;
    const float* srcA = (j2 < 8) ? x : h;
    int kbA = (j2 & 7) * 32;
#pragma unroll
    for (int p = 0; p < 4; ++p)
      gload16(srcA + fA[p] + kbA, db + ldsA[p] - B_OFF + B_OFF);  // A region
#pragma unroll
    for (int p = 0; p < 2; ++p)
      gload16(Bp + fB[p] + j2 * 32, db + ldsB[p]);
  };

  // Prologue: halves 0,1 in flight.
  stage(0);
  stage(1);

#pragma unroll
  for (int j = 0; j < 16; ++j) {
    if (j == 15)
      asm volatile("s_waitcnt vmcnt(0)" ::: "memory");
    else
      asm volatile("s_waitcnt vmcnt(6)" ::: "memory");
    SBAR();
    if (j <= 13) stage(j + 2);

    const char* sb = smem + (j % 3) * SLOT_BYTES;
    half8 bv[4];
#pragma unroll
    for (int nf = 0; nf < 4; ++nf)
      bv[nf] = *reinterpret_cast<const half8*>(sb + offB[nf]);
#pragma unroll
    for (int bat = 0; bat < 2; ++bat) {
      f32x4 a0[4], a1[4];
#pragma unroll
      for (int q = 0; q < 4; ++q) {
        int mf = bat * 4 + q;
        a0[q] = *reinterpret_cast<const f32x4*>(sb + offA[mf][0]);
        a1[q] = *reinterpret_cast<const f32x4*>(sb + offA[mf][1]);
      }
      __builtin_amdgcn_s_setprio(1);
#pragma unroll
      for (int q = 0; q < 4; ++q) {
        int mf = bat * 4 + q;
        half8 av;
        av[0] = (_Float16)a0[q][0]; av[1] = (_Float16)a0[q][1];
        av[2] = (_Float16)a0[q][2]; av[3] = (_Float16)a0[q][3];
        av[4] = (_Float16)a1[q][0]; av[5] = (_Float16)a1[q][1];
        av[6] = (_Float16)a1[q][2]; av[7] = (_Float16)a1[q][3];
#pragma unroll
        for (int nf = 0; nf < 4; ++nf)
          acc[mf][nf] = __builtin_amdgcn_mfma_f32_16x16x32_f16(
              av, bv[nf], acc[mf][nf], 0, 0, 0);
      }
      __builtin_amdgcn_s_setprio(0);
    }
  }

  // --- Epilogue: n-frag == gate (0=f,1=i,2=o,3=c); C/D: col=lane&15,
  // row=(lane>>4)*4+reg.
  int col = (bn * 4 + wcn) * 16 + l15;  // logical column in [0,256)
  float vbf = bf_[col], vbi = bi_[col], vbo = bo_[col], vbc = bc_[col];
#pragma unroll
  for (int mf = 0; mf < 8; ++mf) {
#pragma unroll
    for (int r = 0; r < 4; ++r) {
      long row = (long)(bm * 256 + wr * 128 + mf * 16 + lg * 4 + r);
      float zf = acc[mf][0][r] + vbf;
      float zi = acc[mf][1][r] + vbi;
      float zo = acc[mf][2][r] + vbo;
      float zg = acc[mf][3][r] + vbc;
      float fg = fast_sigmoid(zf);
      float ig = fast_sigmoid(zi);
      float og = fast_sigmoid(zo);
      float gg = fast_tanh(zg);
      float cv = cin[row * 256 + col];
      float cn = cv * fg + gg * ig;
      float hn = og * fast_tanh(cn);
      out[row * 256 + col] = cn;
      out[BHSZ + row * 256 + col] = hn;
    }
  }
}

// ---------------------------------------------------------------------------
extern "C" void kernel_launch(void* const* d_in, const int* in_sizes, int n_in,
                              void* d_out, int out_size, void* d_ws, size_t ws_size,
                              hipStream_t stream) {
  const float* x  = (const float*)d_in[0];
  const float* c  = (const float*)d_in[1];
  const float* h  = (const float*)d_in[2];
  const float* Wi = (const float*)d_in[3];
  const float* Ui = (const float*)d_in[4];
  const float* bi = (const float*)d_in[5];
  const float* Wf = (const float*)d_in[6];
  const float* Uf = (const float*)d_in[7];
  const float* bf = (const float*)d_in[8];
  const float* Wc = (const float*)d_in[9];
  const float* Uc = (const float*)d_in[10];
  const float* bc = (const float*)d_in[11];
  const float* Wo = (const float*)d_in[12];
  const float* Uo = (const float*)d_in[13];
  const float* bo = (const float*)d_in[14];

  _Float16* Bp = (_Float16*)d_ws;  // 1 MB packed weights

  pack_b<<<2048, 256, 0, stream>>>(Wf, Uf, Wi, Ui, Wo, Uo, Wc, Uc, Bp);
  lstm_fused<<<1024, 512, 3 * SLOT_BYTES, stream>>>(x, h, Bp, c, bf, bi, bo,
                                                    bc, (float*)d_out);
}